// Round 1
// baseline (6619.609 us; speedup 1.0000x reference)
//
#include <hip/hip_runtime.h>
#include <math.h>

#define BTOT   16384
#define BC     64          // paths per block
#define NWAVES 8           // 512 threads
#define LAYER  128

static __device__ __forceinline__ float lrelu(float x) { return x >= 0.f ? x : 0.01f * x; }

// constants (match numpy double -> float32)
#define DT_F    ((float)(1.0/96.0))
#define SQDT_F  (0.10206207261596575f)
#define DF_F    (0.99968754882437816f)
#define RFR_F   (0.03f)

// out[r][c] = lrelu( sum_k Wt[k*128 + r] * hin[k][c] + bias[r] ), r in [wave*16, wave*16+16)
__device__ __forceinline__ void hidden_layer(
    const float* __restrict__ Wt, const float* __restrict__ bias,
    const float (*__restrict__ hin)[BC], float (*__restrict__ hout)[BC],
    int wave, int lane)
{
    const int r0 = wave * 16;
    float acc[16];
#pragma unroll
    for (int j = 0; j < 16; ++j) acc[j] = 0.f;
#pragma unroll 2
    for (int k = 0; k < LAYER; ++k) {
        const float hv = hin[k][lane];
        const float* wr = Wt + k * LAYER + r0;   // wave-uniform -> s_load
#pragma unroll
        for (int j = 0; j < 16; ++j) acc[j] = fmaf(wr[j], hv, acc[j]);
    }
#pragma unroll
    for (int j = 0; j < 16; ++j) hout[r0 + j][lane] = lrelu(acc[j] + bias[r0 + j]);
}

__global__ __launch_bounds__(512, 2)
void sim_kernel(const float* __restrict__ normals, const float* __restrict__ strikes,
                const float* __restrict__ levWin, const float* __restrict__ levbin,
                const float* __restrict__ levbh,  const float* __restrict__ levWout,
                const float* __restrict__ levbout,
                const float* __restrict__ hedWin, const float* __restrict__ hedbin,
                const float* __restrict__ hedbh,  const float* __restrict__ hedbout,
                const float* __restrict__ wtLev,    // [8][3][128][128] k-major
                const float* __restrict__ wtHed,    // [8][3][128][128] k-major
                const float* __restrict__ wtHedOut, // [8][128][64]     k-major
                double* __restrict__ acc)
{
    __shared__ float sh_h[2][LAYER][BC];   // 64 KB ping-pong activations
    __shared__ float sh_hedg[64][BC];      // 16 KB hedging state
    __shared__ float sh_red[NWAVES][BC];   // 2 KB lev-out reduction
    __shared__ float sh_S[BC], sh_Snew[BC], sh_hcoef[BC];

    const int tid  = threadIdx.x;
    const int lane = tid & 63;
    const int wave = __builtin_amdgcn_readfirstlane(tid >> 6);
    const int bp0  = blockIdx.x * BC;

    // init state
    for (int j = wave; j < 64; j += NWAVES) sh_hedg[j][lane] = 0.f;
    if (tid < BC) sh_S[tid] = 1.0f;   // S0
    __syncthreads();

    float dfim1 = 1.0f;               // df^(i-1)
    for (int i = 1; i <= 96; ++i) {
        const int idx = (i - 1) / 12;
        const float t = (float)(i - 1) * DT_F;

        // ---------- lev MLP ----------
        {   // layer 1: input [t, S]
            const float* W = levWin + idx * LAYER * 2;
            const float* b = levbin + idx * LAYER;
            const int r0 = wave * 16;
            const float Sc = sh_S[lane];
#pragma unroll
            for (int j = 0; j < 16; ++j) {
                const int r = r0 + j;
                sh_h[0][r][lane] = lrelu(fmaf(W[2*r], t, fmaf(W[2*r+1], Sc, b[r])));
            }
        }
        __syncthreads();
        hidden_layer(wtLev + ((size_t)(idx*3+0) << 14), levbh + idx*384,       sh_h[0], sh_h[1], wave, lane);
        __syncthreads();
        hidden_layer(wtLev + ((size_t)(idx*3+1) << 14), levbh + idx*384 + 128, sh_h[1], sh_h[0], wave, lane);
        __syncthreads();
        hidden_layer(wtLev + ((size_t)(idx*3+2) << 14), levbh + idx*384 + 256, sh_h[0], sh_h[1], wave, lane);
        __syncthreads();
        {   // lev output (1x128 dot) split over waves
            const float* Wo = levWout + idx * LAYER;
            float p = 0.f;
#pragma unroll
            for (int kk = 0; kk < 16; ++kk) {
                const int k = wave * 16 + kk;
                p = fmaf(Wo[k], sh_h[1][k][lane], p);
            }
            sh_red[wave][lane] = p;
        }
        __syncthreads();
        if (wave == 0) {   // SDE update (one wave, 64 paths)
            float s = 0.f;
#pragma unroll
            for (int w = 0; w < NWAVES; ++w) s += sh_red[w][lane];
            s += levbout[idx];
            const float lev = (s > 20.f) ? s : log1pf(expf(s));   // softplus
            const float S = sh_S[lane];
            const float drift = S * RFR_F / (1.f + fabsf(S * RFR_F) * SQDT_F);
            const float dif   = S * lev   / (1.f + fabsf(S * lev)   * SQDT_F);
            const float dW = SQDT_F * normals[(size_t)(i-1) * BTOT + bp0 + lane];
            sh_Snew[lane]  = S + drift * DT_F + dif * dW;
            sh_hcoef[lane] = dfim1 * (S * dif) * dW;
        }
        __syncthreads();

        // ---------- hed MLP (input uses S_prev) ----------
        {
            const float* W = hedWin + idx * LAYER * 2;
            const float* b = hedbin + idx * LAYER;
            const int r0 = wave * 16;
            const float Sc = sh_S[lane];
#pragma unroll
            for (int j = 0; j < 16; ++j) {
                const int r = r0 + j;
                sh_h[0][r][lane] = lrelu(fmaf(W[2*r], t, fmaf(W[2*r+1], Sc, b[r])));
            }
        }
        __syncthreads();
        hidden_layer(wtHed + ((size_t)(idx*3+0) << 14), hedbh + idx*384,       sh_h[0], sh_h[1], wave, lane);
        __syncthreads();
        hidden_layer(wtHed + ((size_t)(idx*3+1) << 14), hedbh + idx*384 + 128, sh_h[1], sh_h[0], wave, lane);
        __syncthreads();
        hidden_layer(wtHed + ((size_t)(idx*3+2) << 14), hedbh + idx*384 + 256, sh_h[0], sh_h[1], wave, lane);
        __syncthreads();
        {   // hed output (64 rows) + hedging accumulation; wave w owns rows 8w..8w+7
            const float* Wc = wtHedOut + ((size_t)idx << 13);
            const float* bo = hedbout + idx * 64;
            const int j0 = wave * 8;
            float a[8];
#pragma unroll
            for (int j = 0; j < 8; ++j) a[j] = 0.f;
#pragma unroll 2
            for (int k = 0; k < LAYER; ++k) {
                const float hv = sh_h[1][k][lane];
                const float* wr = Wc + k * 64 + j0;   // wave-uniform -> s_load
#pragma unroll
                for (int j = 0; j < 8; ++j) a[j] = fmaf(wr[j], hv, a[j]);
            }
            const float hc = sh_hcoef[lane];
#pragma unroll
            for (int j = 0; j < 8; ++j)
                sh_hedg[j0 + j][lane] = fmaf(hc, a[j] + bo[j0 + j], sh_hedg[j0 + j][lane]);
        }
        const float dfi = dfim1 * DF_F;   // df^i
        __syncthreads();

        if ((i % 12) == 0) {   // maturity: per-strike mean/var partial sums
            const int m = i / 12 - 1;
            const float K = strikes[wave];
            const float Sc = sh_Snew[lane];
            const float sim = dfi * fmaxf(Sc - K, 0.f) - sh_hedg[wave * 8 + m][lane];
            float rs = sim, rq = sim * sim;
#pragma unroll
            for (int off = 32; off > 0; off >>= 1) {
                rs += __shfl_down(rs, off);
                rq += __shfl_down(rq, off);
            }
            if (lane == 0) {
                atomicAdd(&acc[wave * 8 + m], (double)rs);
                atomicAdd(&acc[64 + wave * 8 + m], (double)rq);
            }
        }
        if (tid < BC) sh_S[tid] = sh_Snew[tid];
        dfim1 = dfi;
        __syncthreads();
    }
}

// transpose weights to k-major + zero accumulators
__global__ void prep_kernel(const float* __restrict__ levWh, const float* __restrict__ hedWh,
                            const float* __restrict__ hedWout,
                            float* __restrict__ wtLev, float* __restrict__ wtHed,
                            float* __restrict__ wtHedOut, double* __restrict__ acc)
{
    const int tid = blockIdx.x * blockDim.x + threadIdx.x;
    const int nth = gridDim.x * blockDim.x;
    if (tid < 128) acc[tid] = 0.0;
    for (int i = tid; i < 8 * 3 * 128 * 128; i += nth) {
        const int in  = i & 127;
        const int out = (i >> 7) & 127;
        const int g   = i >> 14;              // idx*3 + layer
        wtLev[((size_t)g << 14) + (in << 7) + out] = levWh[((size_t)g << 14) + (out << 7) + in];
        wtHed[((size_t)g << 14) + (in << 7) + out] = hedWh[((size_t)g << 14) + (out << 7) + in];
    }
    for (int i = tid; i < 8 * 128 * 64; i += nth) {
        const int o = i & 63;
        const int k = (i >> 6) & 127;
        const int idx = i >> 13;
        wtHedOut[((size_t)idx << 13) + (k << 6) + o] = hedWout[((size_t)idx << 13) + (o << 7) + k];
    }
}

__global__ void finalize_kernel(const double* __restrict__ acc, float* __restrict__ out)
{
    const int t = threadIdx.x;
    if (t < 64) {
        const double s = acc[t], q = acc[64 + t];
        const double mean = s / 16384.0;
        const double var  = (q - s * s / 16384.0) / 16383.0;
        out[t]      = (float)mean;   // prices [8][8]
        out[64 + t] = (float)var;    // variance [8][8]
    }
}

extern "C" void kernel_launch(void* const* d_in, const int* in_sizes, int n_in,
                              void* d_out, int out_size, void* d_ws, size_t ws_size,
                              hipStream_t stream)
{
    const float* normals = (const float*)d_in[0];
    const float* strikes = (const float*)d_in[1];
    const float* levWin  = (const float*)d_in[2];
    const float* levbin  = (const float*)d_in[3];
    const float* levWh   = (const float*)d_in[4];
    const float* levbh   = (const float*)d_in[5];
    const float* levWout = (const float*)d_in[6];
    const float* levbout = (const float*)d_in[7];
    const float* hedWin  = (const float*)d_in[8];
    const float* hedbin  = (const float*)d_in[9];
    const float* hedWh   = (const float*)d_in[10];
    const float* hedbh   = (const float*)d_in[11];
    const float* hedWout = (const float*)d_in[12];
    const float* hedbout = (const float*)d_in[13];

    float* wtLev    = (float*)d_ws;              // 393216 floats
    float* wtHed    = wtLev + 393216;            // 393216 floats
    float* wtHedOut = wtHed + 393216;            // 65536 floats
    double* acc     = (double*)(wtHedOut + 65536); // 128 doubles (8-byte aligned)

    prep_kernel<<<256, 256, 0, stream>>>(levWh, hedWh, hedWout, wtLev, wtHed, wtHedOut, acc);
    sim_kernel<<<BTOT / BC, 512, 0, stream>>>(normals, strikes,
                                              levWin, levbin, levbh, levWout, levbout,
                                              hedWin, hedbin, hedbh, hedbout,
                                              wtLev, wtHed, wtHedOut, acc);
    finalize_kernel<<<1, 64, 0, stream>>>(acc, (float*)d_out);
}

// Round 2
// 1350.697 us; speedup vs baseline: 4.9009x; 4.9009x over previous
//
#include <hip/hip_runtime.h>
#include <math.h>

typedef __attribute__((ext_vector_type(8)))  short  short8;
typedef __attribute__((ext_vector_type(4)))  short  short4v;
typedef __attribute__((ext_vector_type(16))) float  f32x16;
typedef __attribute__((ext_vector_type(4)))  float  f32x4v;

#define DT_F    ((float)(1.0/96.0))
#define SQDT_F  (0.10206207261596575f)
#define DF_F    (0.99968754882437816f)
#define RFR_F   (0.03f)

// swizzled LDS index for activations stored as [c][k] bf16 (128 k per col)
#define SWZ(c,k) (((c)<<7) + ((k) ^ (((c)&7)<<3)))

static __device__ __forceinline__ short f2bf(float x) {
    return __builtin_bit_cast(short, (__bf16)x);
}
static __device__ __forceinline__ float bf2f(short h) {
    return (float)__builtin_bit_cast(__bf16, h);
}

// ---------------- layer 1: [t,S] -> 128, rows 32*wv+8g..+8, cols c15+{0,16,32,48}
__device__ __forceinline__ void layer1(const float* __restrict__ Win, const float* __restrict__ bin_,
        float t, const float* __restrict__ sScur, ushort* __restrict__ out, int wv, int l)
{
    const int g = l >> 4, c15 = l & 15;
    const int r0 = (wv << 5) + (g << 3);
    float a8[8], w1[8];
#pragma unroll
    for (int jj = 0; jj < 8; ++jj) {
        const int r = r0 + jj;
        a8[jj] = fmaf(Win[2*r], t, bin_[r]);
        w1[jj] = Win[2*r + 1];
    }
#pragma unroll
    for (int cc = 0; cc < 4; ++cc) {
        const int c = c15 + (cc << 4);
        const float S = sScur[c];
        short8 v;
#pragma unroll
        for (int jj = 0; jj < 8; ++jj) {
            float h = fmaf(w1[jj], S, a8[jj]);
            h = fmaxf(h, 0.01f * h);            // leaky relu
            v[jj] = f2bf(h);
        }
        *(short8*)&out[SWZ(c, r0)] = v;
    }
}

// ---------------- hidden 128x128 layer via 32x32x16 MFMA, wave owns rows 32*wv..+32
__device__ __forceinline__ void hidden32(const ushort* __restrict__ WFm, const float* __restrict__ bias,
        const ushort* __restrict__ bin, ushort* __restrict__ bout, int wv, int l)
{
    const int c0 = l & 31;
    const int l5 = l >> 5;
    const int kr = l5 << 3;
    f32x16 acc0 = {0,0,0,0,0,0,0,0,0,0,0,0,0,0,0,0};
    f32x16 acc1 = {0,0,0,0,0,0,0,0,0,0,0,0,0,0,0,0};
    const short8* fb = (const short8*)(WFm + (wv << 13));   // rb = wv
#pragma unroll
    for (int kc = 0; kc < 8; ++kc) {
        short8 ah = fb[((kc << 1) + 0) * 64 + l];           // W_hi fragment
        short8 al = fb[((kc << 1) + 1) * 64 + l];           // W_lo fragment
        const int k0 = (kc << 4) + kr;
        short8 b0 = *(const short8*)&bin[SWZ(c0,      k0)];
        short8 b1 = *(const short8*)&bin[SWZ(c0 + 32, k0)];
        acc0 = __builtin_amdgcn_mfma_f32_32x32x16_bf16(ah, b0, acc0, 0, 0, 0);
        acc0 = __builtin_amdgcn_mfma_f32_32x32x16_bf16(al, b0, acc0, 0, 0, 0);
        acc1 = __builtin_amdgcn_mfma_f32_32x32x16_bf16(ah, b1, acc1, 0, 0, 0);
        acc1 = __builtin_amdgcn_mfma_f32_32x32x16_bf16(al, b1, acc1, 0, 0, 0);
    }
    // C/D: row = (reg&3) + 8*(reg>>2) + 4*l5, col = c0
#pragma unroll
    for (int q = 0; q < 4; ++q) {
        const int rloc = (q << 3) + (l5 << 2);
        const f32x4v bq = *(const f32x4v*)&bias[(wv << 5) + rloc];
        short4v o0, o1;
#pragma unroll
        for (int ii = 0; ii < 4; ++ii) {
            float x0 = acc0[(q << 2) + ii] + bq[ii]; o0[ii] = f2bf(fmaxf(x0, 0.01f * x0));
            float x1 = acc1[(q << 2) + ii] + bq[ii]; o1[ii] = f2bf(fmaxf(x1, 0.01f * x1));
        }
        *(short4v*)&bout[SWZ(c0,      (wv << 5) + rloc)] = o0;
        *(short4v*)&bout[SWZ(c0 + 32, (wv << 5) + rloc)] = o1;
    }
}

__global__ __launch_bounds__(256, 1)
void sim_kernel(const float* __restrict__ normals, const float* __restrict__ strikes,
                const float* __restrict__ levWin, const float* __restrict__ levbin,
                const float* __restrict__ levbh,  const float* __restrict__ levWout,
                const float* __restrict__ levbout,
                const float* __restrict__ hedWin, const float* __restrict__ hedbin,
                const float* __restrict__ hedbh,  const float* __restrict__ hedbout,
                const ushort* __restrict__ WF, double* __restrict__ accD)
{
    __shared__ ushort bufA[64 * 128];
    __shared__ ushort bufB[64 * 128];
    __shared__ float  sS[2][64];
    __shared__ float  sHc[64];

    const int tid = threadIdx.x;
    const int wv  = tid >> 6;
    const int l   = tid & 63;
    const int g   = l >> 4;
    const int c15 = l & 15;
    const int bp0 = blockIdx.x * 64;

    if (tid < 64) sS[0][tid] = 1.0f;
    float hedg[4][4];
#pragma unroll
    for (int a = 0; a < 4; ++a)
#pragma unroll
        for (int b = 0; b < 4; ++b) hedg[a][b] = 0.f;
    float dfim1 = 1.0f;
    __syncthreads();

    for (int i = 1; i <= 96; ++i) {
        const int idx = (i - 1) / 12;
        const float t = (float)(i - 1) * DT_F;
        const float* sScur = sS[(i - 1) & 1];
        float* sSnxt = sS[i & 1];
        const ushort* WFi = WF + (size_t)idx * 212992;

        // lev MLP
        layer1(levWin + idx * 256, levbin + (idx << 7), t, sScur, bufA, wv, l);
        __syncthreads();
        hidden32(WFi,           levbh + (idx * 3 + 0) * 128, bufA, bufB, wv, l);
        __syncthreads();
        hidden32(WFi + 32768,   levbh + (idx * 3 + 1) * 128, bufB, bufA, wv, l);
        __syncthreads();
        hidden32(WFi + 65536,   levbh + (idx * 3 + 2) * 128, bufA, bufB, wv, l);
        __syncthreads();

        // lev-out + SDE (reads bufB; all waves redundantly) ∥ hed layer1 -> bufA
        {
            const float* Wo = levWout + (idx << 7);
            float wk[32];
#pragma unroll
            for (int kb = 0; kb < 8; ++kb)
                *(f32x4v*)&wk[4 * kb] = *(const f32x4v*)&Wo[(g << 5) + (kb << 2)];
            const float bo = levbout[idx];
#pragma unroll
            for (int cc = 0; cc < 4; ++cc) {
                const int c = c15 + (cc << 4);
                float p = 0.f;
#pragma unroll
                for (int kb = 0; kb < 4; ++kb) {
                    short8 hv = *(const short8*)&bufB[SWZ(c, (g << 5) + (kb << 3))];
#pragma unroll
                    for (int j = 0; j < 8; ++j) p = fmaf(bf2f(hv[j]), wk[(kb << 3) + j], p);
                }
                p += __shfl_xor(p, 16);
                p += __shfl_xor(p, 32);
                p += bo;
                const float lv = (p > 20.f) ? p : log1pf(expf(p));   // softplus
                const float S = sScur[c];
                const float drift = S * RFR_F / (1.f + fabsf(S * RFR_F) * SQDT_F);
                const float dif   = S * lv    / (1.f + fabsf(S * lv)   * SQDT_F);
                const float dW = SQDT_F * normals[(i - 1) * 16384 + bp0 + c];
                const float Sn = S + drift * DT_F + dif * dW;
                if (g == 0) { sSnxt[c] = Sn; sHc[c] = dfim1 * (S * dif) * dW; }
            }
        }
        layer1(hedWin + idx * 256, hedbin + (idx << 7), t, sScur, bufA, wv, l);
        __syncthreads();
        hidden32(WFi + 3 * 32768, hedbh + (idx * 3 + 0) * 128, bufA, bufB, wv, l);
        __syncthreads();
        hidden32(WFi + 4 * 32768, hedbh + (idx * 3 + 1) * 128, bufB, bufA, wv, l);
        __syncthreads();
        hidden32(WFi + 5 * 32768, hedbh + (idx * 3 + 2) * 128, bufA, bufB, wv, l);
        __syncthreads();

        const float dfi = dfim1 * DF_F;
        // hed-out 64x128 via 16x16x32 MFMA (wave owns rows 16*wv..+16) + hedging + maturity
        {
            f32x4v acc0 = {0,0,0,0}, acc1 = {0,0,0,0}, acc2 = {0,0,0,0}, acc3 = {0,0,0,0};
            const short8* fb = (const short8*)(WFi + 196608 + (wv << 12));
#pragma unroll
            for (int kcq = 0; kcq < 4; ++kcq) {
                short8 ah = fb[((kcq << 1) + 0) * 64 + l];
                short8 al = fb[((kcq << 1) + 1) * 64 + l];
                const int k0 = (kcq << 5) + (g << 3);
                short8 b0 = *(const short8*)&bufB[SWZ(c15,      k0)];
                short8 b1 = *(const short8*)&bufB[SWZ(16 + c15, k0)];
                short8 b2 = *(const short8*)&bufB[SWZ(32 + c15, k0)];
                short8 b3 = *(const short8*)&bufB[SWZ(48 + c15, k0)];
                acc0 = __builtin_amdgcn_mfma_f32_16x16x32_bf16(ah, b0, acc0, 0, 0, 0);
                acc0 = __builtin_amdgcn_mfma_f32_16x16x32_bf16(al, b0, acc0, 0, 0, 0);
                acc1 = __builtin_amdgcn_mfma_f32_16x16x32_bf16(ah, b1, acc1, 0, 0, 0);
                acc1 = __builtin_amdgcn_mfma_f32_16x16x32_bf16(al, b1, acc1, 0, 0, 0);
                acc2 = __builtin_amdgcn_mfma_f32_16x16x32_bf16(ah, b2, acc2, 0, 0, 0);
                acc2 = __builtin_amdgcn_mfma_f32_16x16x32_bf16(al, b2, acc2, 0, 0, 0);
                acc3 = __builtin_amdgcn_mfma_f32_16x16x32_bf16(ah, b3, acc3, 0, 0, 0);
                acc3 = __builtin_amdgcn_mfma_f32_16x16x32_bf16(al, b3, acc3, 0, 0, 0);
            }
            // C/D row j = 16*wv + 4g + i ; col = 16*ct + c15
            const f32x4v bo4 = *(const f32x4v*)&hedbout[(idx << 6) + (wv << 4) + (g << 2)];
            const float hc0 = sHc[c15], hc1 = sHc[16 + c15], hc2 = sHc[32 + c15], hc3 = sHc[48 + c15];
#pragma unroll
            for (int ii = 0; ii < 4; ++ii) {
                hedg[0][ii] = fmaf(hc0, acc0[ii] + bo4[ii], hedg[0][ii]);
                hedg[1][ii] = fmaf(hc1, acc1[ii] + bo4[ii], hedg[1][ii]);
                hedg[2][ii] = fmaf(hc2, acc2[ii] + bo4[ii], hedg[2][ii]);
                hedg[3][ii] = fmaf(hc3, acc3[ii] + bo4[ii], hedg[3][ii]);
            }
            if ((i % 12) == 0) {
                const int m = i / 12 - 1;
                const int isel = m & 3;
                const bool active = ((m >> 2) == (g & 1));
                const int ks = (wv << 1) + (g >> 1);
                float s_ = 0.f, q_ = 0.f;
                if (active) {
                    const float K = strikes[ks];
#pragma unroll
                    for (int ct = 0; ct < 4; ++ct) {
                        const float* hrow = hedg[ct];
                        const float hv = (isel == 0) ? hrow[0] : (isel == 1) ? hrow[1]
                                        : (isel == 2) ? hrow[2] : hrow[3];
                        const float Sn = sSnxt[(ct << 4) + c15];
                        const float sim = dfi * fmaxf(Sn - K, 0.f) - hv;
                        s_ += sim; q_ += sim * sim;
                    }
                }
#pragma unroll
                for (int off = 1; off < 16; off <<= 1) {
                    s_ += __shfl_xor(s_, off);
                    q_ += __shfl_xor(q_, off);
                }
                if (active && c15 == 0) {
                    const int rep = blockIdx.x & 31;
                    atomicAdd(&accD[rep * 128 + ks * 8 + m], (double)s_);
                    atomicAdd(&accD[rep * 128 + 64 + ks * 8 + m], (double)q_);
                }
            }
        }
        dfim1 = dfi;
        // no trailing barrier needed: next phase writes bufA only, ordered by next barrier
    }
}

// ---------------- prep: pack weights into MFMA fragment order (hi/lo bf16) + zero accumulators
__global__ void prep_kernel(const float* __restrict__ levWh, const float* __restrict__ hedWh,
                            const float* __restrict__ hedWout,
                            ushort* __restrict__ WF, double* __restrict__ accD)
{
    const long long stride = (long long)gridDim.x * blockDim.x;
    const long long t0 = (long long)blockIdx.x * blockDim.x + threadIdx.x;
    for (long long e = t0; e < 1703936LL; e += stride) {
        const int idx = (int)(e / 212992);
        const int rem = (int)(e % 212992);
        float val;
        int part;
        if (rem < 196608) {                       // 6 hidden matrices, 32x32x16 frags
            const int m    = rem >> 15;           // /32768
            const int r2   = rem & 32767;
            const int slot = r2 >> 9;             // (rb*8+kc)*2+part
            const int rb   = slot >> 4;
            const int kc   = (slot >> 1) & 7;
            part           = slot & 1;
            const int lane = (r2 >> 3) & 63;
            const int j    = r2 & 7;
            const int r = (rb << 5) + (lane & 31);
            const int k = (kc << 4) + ((lane >> 5) << 3) + j;
            const float* src = (m < 3) ? levWh : hedWh;
            const int mm = (m < 3) ? m : m - 3;
            val = src[(((idx * 3 + mm) << 7) + r) * 128 + k];
        } else {                                  // hed-out 64x128, 16x16x32 frags
            const int r3   = rem - 196608;
            const int slot = r3 >> 9;             // (rb*4+kcq)*2+part
            const int rb   = slot >> 3;
            const int kcq  = (slot >> 1) & 3;
            part           = slot & 1;
            const int lane = (r3 >> 3) & 63;
            const int j    = r3 & 7;
            const int r = (rb << 4) + (lane & 15);
            const int k = (kcq << 5) + ((lane >> 4) << 3) + j;
            val = hedWout[(idx << 13) + (r << 7) + k];
        }
        const short hi = f2bf(val);
        WF[e] = (ushort)((part == 0) ? hi : f2bf(val - bf2f(hi)));
    }
    for (long long e = t0; e < 4096; e += stride) accD[e] = 0.0;
}

__global__ void finalize_kernel(const double* __restrict__ accD, float* __restrict__ out)
{
    const int t = threadIdx.x;
    if (t < 64) {
        double s = 0.0, q = 0.0;
        for (int rep = 0; rep < 32; ++rep) {
            s += accD[rep * 128 + t];
            q += accD[rep * 128 + 64 + t];
        }
        out[t]      = (float)(s / 16384.0);
        out[64 + t] = (float)((q - s * s / 16384.0) / 16383.0);
    }
}

extern "C" void kernel_launch(void* const* d_in, const int* in_sizes, int n_in,
                              void* d_out, int out_size, void* d_ws, size_t ws_size,
                              hipStream_t stream)
{
    const float* normals = (const float*)d_in[0];
    const float* strikes = (const float*)d_in[1];
    const float* levWin  = (const float*)d_in[2];
    const float* levbin  = (const float*)d_in[3];
    const float* levWh   = (const float*)d_in[4];
    const float* levbh   = (const float*)d_in[5];
    const float* levWout = (const float*)d_in[6];
    const float* levbout = (const float*)d_in[7];
    const float* hedWin  = (const float*)d_in[8];
    const float* hedbin  = (const float*)d_in[9];
    const float* hedWh   = (const float*)d_in[10];
    const float* hedbh   = (const float*)d_in[11];
    const float* hedWout = (const float*)d_in[12];
    const float* hedbout = (const float*)d_in[13];

    ushort* WF   = (ushort*)d_ws;                                // 1,703,936 ushorts
    double* accD = (double*)((char*)d_ws + 3407872);             // 4096 doubles

    prep_kernel<<<2048, 256, 0, stream>>>(levWh, hedWh, hedWout, WF, accD);
    sim_kernel<<<256, 256, 0, stream>>>(normals, strikes,
                                        levWin, levbin, levbh, levWout, levbout,
                                        hedWin, hedbin, hedbh, hedbout,
                                        WF, accD);
    finalize_kernel<<<1, 64, 0, stream>>>(accD, (float*)d_out);
}

// Round 3
// 574.041 us; speedup vs baseline: 11.5316x; 2.3530x over previous
//
#include <hip/hip_runtime.h>
#include <math.h>

typedef __attribute__((ext_vector_type(8)))  short  short8;
typedef __attribute__((ext_vector_type(4)))  short  short4v;
typedef __attribute__((ext_vector_type(16))) float  f32x16;
typedef __attribute__((ext_vector_type(4)))  float  f32x4v;

#define DT_F    ((float)(1.0/96.0))
#define SQDT_F  (0.10206207261596575f)
#define DF_F    (0.99968754882437816f)
#define RFR_F   (0.03f)

// swizzled LDS index for activations stored as [c][k] bf16 (byte ^= (c&7)<<4)
#define SWZ(c,k) (((c)<<7) + ((k) ^ (((c)&7)<<3)))

static __device__ __forceinline__ short f2bf(float x) {
    return __builtin_bit_cast(short, (__bf16)x);
}
static __device__ __forceinline__ float bf2f(short h) {
    return (float)__builtin_bit_cast(__bf16, h);
}

// layer 1: [t,S] -> 128 rows; wave-of-MLP wvm owns rows 32*wvm..+32, all 64 cols
__device__ __forceinline__ void layer1(const float* __restrict__ Win, const float* __restrict__ bin_,
        float t, const float* __restrict__ sScur, ushort* __restrict__ out, int wvm, int l)
{
    const int g = l >> 4, c15 = l & 15;
    const int r0 = (wvm << 5) + (g << 3);
    float a8[8], w1[8];
#pragma unroll
    for (int jj = 0; jj < 8; ++jj) {
        const int r = r0 + jj;
        a8[jj] = fmaf(Win[2*r], t, bin_[r]);
        w1[jj] = Win[2*r + 1];
    }
#pragma unroll
    for (int cc = 0; cc < 4; ++cc) {
        const int c = c15 + (cc << 4);
        const float S = sScur[c];
        short8 v;
#pragma unroll
        for (int jj = 0; jj < 8; ++jj) {
            float h = fmaf(w1[jj], S, a8[jj]);
            h = fmaxf(h, 0.01f * h);            // leaky relu
            v[jj] = f2bf(h);
        }
        *(short8*)&out[SWZ(c, r0)] = v;
    }
}

// hidden 128x128 layer, bf16 weights, 32x32x16 MFMA; wvm owns rows 32*wvm..+32
// 4 independent accumulator chains (even/odd kc x 2 col-tiles)
__device__ __forceinline__ void hidden32(const ushort* __restrict__ WFm, const float* __restrict__ bias,
        const ushort* __restrict__ bin, ushort* __restrict__ bout, int wvm, int l)
{
    const int c0 = l & 31;
    const int l5 = l >> 5;
    const int kr = l5 << 3;
    f32x16 a0e = {0,0,0,0,0,0,0,0,0,0,0,0,0,0,0,0};
    f32x16 a0o = a0e, a1e = a0e, a1o = a0e;
    const short8* fb = (const short8*)(WFm + (wvm << 12));   // rb = wvm
#pragma unroll
    for (int kc = 0; kc < 8; kc += 2) {
        short8 aE = fb[kc * 64 + l];
        short8 aO = fb[(kc + 1) * 64 + l];
        const int k0e = (kc << 4) + kr;
        const int k0o = k0e + 16;
        short8 b0e = *(const short8*)&bin[SWZ(c0,      k0e)];
        short8 b1e = *(const short8*)&bin[SWZ(c0 + 32, k0e)];
        short8 b0o = *(const short8*)&bin[SWZ(c0,      k0o)];
        short8 b1o = *(const short8*)&bin[SWZ(c0 + 32, k0o)];
        a0e = __builtin_amdgcn_mfma_f32_32x32x16_bf16(aE, b0e, a0e, 0, 0, 0);
        a1e = __builtin_amdgcn_mfma_f32_32x32x16_bf16(aE, b1e, a1e, 0, 0, 0);
        a0o = __builtin_amdgcn_mfma_f32_32x32x16_bf16(aO, b0o, a0o, 0, 0, 0);
        a1o = __builtin_amdgcn_mfma_f32_32x32x16_bf16(aO, b1o, a1o, 0, 0, 0);
    }
    const f32x16 acc0 = a0e + a0o;
    const f32x16 acc1 = a1e + a1o;
    // C/D: row = (reg&3) + 8*(reg>>2) + 4*l5, col = c0
#pragma unroll
    for (int q = 0; q < 4; ++q) {
        const int rloc = (q << 3) + (l5 << 2);
        const f32x4v bq = *(const f32x4v*)&bias[(wvm << 5) + rloc];
        short4v o0, o1;
#pragma unroll
        for (int ii = 0; ii < 4; ++ii) {
            float x0 = acc0[(q << 2) + ii] + bq[ii]; o0[ii] = f2bf(fmaxf(x0, 0.01f * x0));
            float x1 = acc1[(q << 2) + ii] + bq[ii]; o1[ii] = f2bf(fmaxf(x1, 0.01f * x1));
        }
        *(short4v*)&bout[SWZ(c0,      (wvm << 5) + rloc)] = o0;
        *(short4v*)&bout[SWZ(c0 + 32, (wvm << 5) + rloc)] = o1;
    }
}

__global__ __launch_bounds__(512, 1)
void sim_kernel(const float* __restrict__ normals, const float* __restrict__ strikes,
                const float* __restrict__ levWin, const float* __restrict__ levbin,
                const float* __restrict__ levbh,  const float* __restrict__ levWout,
                const float* __restrict__ levbout,
                const float* __restrict__ hedWin, const float* __restrict__ hedbin,
                const float* __restrict__ hedbh,  const float* __restrict__ hedbout,
                const ushort* __restrict__ WF, double* __restrict__ accD)
{
    __shared__ ushort bufL[2][64 * 128];   // lev ping-pong (32 KB)
    __shared__ ushort bufH[2][64 * 128];   // hed ping-pong (32 KB)
    __shared__ float  sS[2][64];
    __shared__ float  sHc[64];

    const int tid  = threadIdx.x;
    const int wv   = tid >> 6;
    const int half = wv >> 2;      // 0 = lev chain, 1 = hed chain
    const int wvm  = wv & 3;
    const int l    = tid & 63;
    const int g    = l >> 4;
    const int c15  = l & 15;
    const int bp0  = blockIdx.x * 64;

    if (tid < 64) sS[0][tid] = 1.0f;
    float hedg[4][4];
#pragma unroll
    for (int a = 0; a < 4; ++a)
#pragma unroll
        for (int b = 0; b < 4; ++b) hedg[a][b] = 0.f;
    float dfim1 = 1.0f;
    __syncthreads();

    for (int i = 1; i <= 96; ++i) {
        const int idx = (i - 1) / 12;
        const float t = (float)(i - 1) * DT_F;
        const float* sScur = sS[(i - 1) & 1];
        float* sSnxt = sS[i & 1];
        const ushort* WFi = WF + (size_t)idx * 106496;

        ushort* A = half ? bufH[0] : bufL[0];
        ushort* B = half ? bufH[1] : bufL[1];
        const float* Win  = (half ? hedWin : levWin) + idx * 256;
        const float* binp = (half ? hedbin : levbin) + (idx << 7);
        const float* bh   = (half ? hedbh  : levbh)  + idx * 384;
        const ushort* Wm  = WFi + ((half * 3) << 14);

        layer1(Win, binp, t, sScur, A, wvm, l);
        __syncthreads();                                    // b1
        hidden32(Wm,              bh,       A, B, wvm, l);
        __syncthreads();                                    // b2
        hidden32(Wm + 16384,      bh + 128, B, A, wvm, l);
        __syncthreads();                                    // b3
        hidden32(Wm + 32768,      bh + 256, A, B, wvm, l);
        __syncthreads();                                    // b4

        const float dfi = dfim1 * DF_F;
        f32x4v acc0 = {0,0,0,0}, acc1 = acc0, acc2 = acc0, acc3 = acc0;
        if (half == 0) {
            // lev-out (1x128 dot) + SDE; wave wvm owns cols 16*wvm..+16
            const float* Wo = levWout + (idx << 7);
            float wk[32];
#pragma unroll
            for (int kb = 0; kb < 8; ++kb)
                *(f32x4v*)&wk[4 * kb] = *(const f32x4v*)&Wo[(g << 5) + (kb << 2)];
            const int c = c15 + (wvm << 4);
            float p = 0.f;
#pragma unroll
            for (int kb = 0; kb < 4; ++kb) {
                short8 hv = *(const short8*)&bufL[1][SWZ(c, (g << 5) + (kb << 3))];
#pragma unroll
                for (int j = 0; j < 8; ++j) p = fmaf(bf2f(hv[j]), wk[(kb << 3) + j], p);
            }
            p += __shfl_xor(p, 16);
            p += __shfl_xor(p, 32);
            p += levbout[idx];
            const float lv = (p > 20.f) ? p : log1pf(expf(p));   // softplus
            const float S = sScur[c];
            const float drift = S * RFR_F / (1.f + fabsf(S * RFR_F) * SQDT_F);
            const float dif   = S * lv    / (1.f + fabsf(S * lv)   * SQDT_F);
            const float dW = SQDT_F * normals[(i - 1) * 16384 + bp0 + c];
            const float Sn = S + drift * DT_F + dif * dW;
            if (g == 0) { sSnxt[c] = Sn; sHc[c] = dfim1 * (S * dif) * dW; }
        } else {
            // hed-out 64x128 via 16x16x32 MFMA; wave wvm owns rows 16*wvm..+16
            const short8* fb = (const short8*)(WFi + 98304 + (wvm << 11));
            __builtin_amdgcn_s_setprio(1);
#pragma unroll
            for (int kcq = 0; kcq < 4; ++kcq) {
                short8 a = fb[kcq * 64 + l];
                const int k0 = (kcq << 5) + (g << 3);
                short8 b0 = *(const short8*)&bufH[1][SWZ(c15,      k0)];
                short8 b1 = *(const short8*)&bufH[1][SWZ(16 + c15, k0)];
                short8 b2 = *(const short8*)&bufH[1][SWZ(32 + c15, k0)];
                short8 b3 = *(const short8*)&bufH[1][SWZ(48 + c15, k0)];
                acc0 = __builtin_amdgcn_mfma_f32_16x16x32_bf16(a, b0, acc0, 0, 0, 0);
                acc1 = __builtin_amdgcn_mfma_f32_16x16x32_bf16(a, b1, acc1, 0, 0, 0);
                acc2 = __builtin_amdgcn_mfma_f32_16x16x32_bf16(a, b2, acc2, 0, 0, 0);
                acc3 = __builtin_amdgcn_mfma_f32_16x16x32_bf16(a, b3, acc3, 0, 0, 0);
            }
            __builtin_amdgcn_s_setprio(0);
        }
        __syncthreads();                                    // b5

        if (half == 1) {
            // hedging accumulation; C/D row j = 16*wvm + 4g + ii, col = 16*ct + c15
            const f32x4v bo4 = *(const f32x4v*)&hedbout[(idx << 6) + (wvm << 4) + (g << 2)];
            const float hc0 = sHc[c15], hc1 = sHc[16 + c15], hc2 = sHc[32 + c15], hc3 = sHc[48 + c15];
#pragma unroll
            for (int ii = 0; ii < 4; ++ii) {
                hedg[0][ii] = fmaf(hc0, acc0[ii] + bo4[ii], hedg[0][ii]);
                hedg[1][ii] = fmaf(hc1, acc1[ii] + bo4[ii], hedg[1][ii]);
                hedg[2][ii] = fmaf(hc2, acc2[ii] + bo4[ii], hedg[2][ii]);
                hedg[3][ii] = fmaf(hc3, acc3[ii] + bo4[ii], hedg[3][ii]);
            }
            if ((i % 12) == 0) {
                const int m = i / 12 - 1;
                const int isel = m & 3;
                const bool active = ((m >> 2) == (g & 1));
                const int ks = (wvm << 1) + (g >> 1);
                float s_ = 0.f, q_ = 0.f;
                if (active) {
                    const float K = strikes[ks];
#pragma unroll
                    for (int ct = 0; ct < 4; ++ct) {
                        const float* hrow = hedg[ct];
                        const float hv = (isel == 0) ? hrow[0] : (isel == 1) ? hrow[1]
                                        : (isel == 2) ? hrow[2] : hrow[3];
                        const float Sn = sSnxt[(ct << 4) + c15];
                        const float sim = dfi * fmaxf(Sn - K, 0.f) - hv;
                        s_ += sim; q_ += sim * sim;
                    }
                }
#pragma unroll
                for (int off = 1; off < 16; off <<= 1) {
                    s_ += __shfl_xor(s_, off);
                    q_ += __shfl_xor(q_, off);
                }
                if (active && c15 == 0) {
                    const int rep = blockIdx.x & 31;
                    atomicAdd(&accD[rep * 128 + ks * 8 + m], (double)s_);
                    atomicAdd(&accD[rep * 128 + 64 + ks * 8 + m], (double)q_);
                }
            }
        }
        dfim1 = dfi;
    }
}

// prep: pack bf16 weights into MFMA fragment order + zero accumulators
// per idx (106496 ushorts): 6x [128x128] hidden (16384 each, 32x32x16 frags) then [64x128] hed-out (8192, 16x16x32 frags)
__global__ void prep_kernel(const float* __restrict__ levWh, const float* __restrict__ hedWh,
                            const float* __restrict__ hedWout,
                            ushort* __restrict__ WF, double* __restrict__ accD)
{
    const long long stride = (long long)gridDim.x * blockDim.x;
    const long long t0 = (long long)blockIdx.x * blockDim.x + threadIdx.x;
    for (long long e = t0; e < 851968LL; e += stride) {
        const int idx = (int)(e / 106496);
        const int rem = (int)(e % 106496);
        float val;
        if (rem < 98304) {                        // 6 hidden matrices
            const int m    = rem >> 14;
            const int r2   = rem & 16383;
            const int slot = r2 >> 9;             // rb*8 + kc
            const int rb   = slot >> 3;
            const int kc   = slot & 7;
            const int lane = (r2 >> 3) & 63;
            const int j    = r2 & 7;
            const int r = (rb << 5) + (lane & 31);
            const int k = (kc << 4) + ((lane >> 5) << 3) + j;
            const float* src = (m < 3) ? levWh : hedWh;
            const int mm = (m < 3) ? m : m - 3;
            val = src[(((idx * 3 + mm) << 7) + r) * 128 + k];
        } else {                                  // hed-out 64x128
            const int r3   = rem - 98304;
            const int slot = r3 >> 9;             // rb*4 + kcq
            const int rb   = slot >> 2;
            const int kcq  = slot & 3;
            const int lane = (r3 >> 3) & 63;
            const int j    = r3 & 7;
            const int r = (rb << 4) + (lane & 15);
            const int k = (kcq << 5) + ((lane >> 4) << 3) + j;
            val = hedWout[(idx << 13) + (r << 7) + k];
        }
        WF[e] = (ushort)f2bf(val);
    }
    for (long long e = t0; e < 4096; e += stride) accD[e] = 0.0;
}

__global__ void finalize_kernel(const double* __restrict__ accD, float* __restrict__ out)
{
    const int t = threadIdx.x;
    if (t < 64) {
        double s = 0.0, q = 0.0;
        for (int rep = 0; rep < 32; ++rep) {
            s += accD[rep * 128 + t];
            q += accD[rep * 128 + 64 + t];
        }
        out[t]      = (float)(s / 16384.0);
        out[64 + t] = (float)((q - s * s / 16384.0) / 16383.0);
    }
}

extern "C" void kernel_launch(void* const* d_in, const int* in_sizes, int n_in,
                              void* d_out, int out_size, void* d_ws, size_t ws_size,
                              hipStream_t stream)
{
    const float* normals = (const float*)d_in[0];
    const float* strikes = (const float*)d_in[1];
    const float* levWin  = (const float*)d_in[2];
    const float* levbin  = (const float*)d_in[3];
    const float* levWh   = (const float*)d_in[4];
    const float* levbh   = (const float*)d_in[5];
    const float* levWout = (const float*)d_in[6];
    const float* levbout = (const float*)d_in[7];
    const float* hedWin  = (const float*)d_in[8];
    const float* hedbin  = (const float*)d_in[9];
    const float* hedWh   = (const float*)d_in[10];
    const float* hedbh   = (const float*)d_in[11];
    const float* hedWout = (const float*)d_in[12];
    const float* hedbout = (const float*)d_in[13];

    ushort* WF   = (ushort*)d_ws;                      // 851,968 ushorts = 1,703,936 B
    double* accD = (double*)((char*)d_ws + 1703936);   // 4096 doubles

    prep_kernel<<<1024, 256, 0, stream>>>(levWh, hedWh, hedWout, WF, accD);
    sim_kernel<<<256, 512, 0, stream>>>(normals, strikes,
                                        levWin, levbin, levbh, levWout, levbout,
                                        hedWin, hedbin, hedbh, hedbout,
                                        WF, accD);
    finalize_kernel<<<1, 64, 0, stream>>>(accD, (float*)d_out);
}